// Round 6
// baseline (281.635 us; speedup 1.0000x reference)
//
#include <hip/hip_runtime.h>
#include <math.h>

#define B_   4
#define N_   4096
#define C_   512
#define C8_  64
#define C2_  256
#define LOG2E 1.44269504f

typedef __attribute__((ext_vector_type(8))) short bf16x8;
typedef __attribute__((ext_vector_type(4))) short bf16x4;
typedef __attribute__((ext_vector_type(4))) float floatx4;
typedef __attribute__((ext_vector_type(16))) float floatx16;

__device__ __forceinline__ short f2bf(float x) {
    unsigned u = __float_as_uint(x);
    u += 0x7fff + ((u >> 16) & 1);          // round-to-nearest-even
    return (short)(u >> 16);
}
// (bf(a) | bf(b)<<16) with round-half-up: 2 adds + 1 v_perm
__device__ __forceinline__ unsigned pack2bf_fast(float a, float b) {
    unsigned ua = __float_as_uint(a) + 0x8000u;
    unsigned ub = __float_as_uint(b) + 0x8000u;
    return __builtin_amdgcn_perm(ub, ua, 0x07060302u);
}
__device__ __forceinline__ float bf2f(short s) {
    return __uint_as_float(((unsigned)(unsigned short)s) << 16);
}

union U8 { bf16x8 v; unsigned u[4]; };

// ---------------------------------------------------------------------------
// Kernel 0: weight prep.  WcatT[384][512] = [Wf|Wg|Wh]^T,  WoT[512][256] = Wo^T
// ---------------------------------------------------------------------------
__global__ __launch_bounds__(256) void convert_w(
    const float* __restrict__ Wf, const float* __restrict__ Wg,
    const float* __restrict__ Wh, const float* __restrict__ Wo,
    short* __restrict__ WcatT, short* __restrict__ WoT)
{
    int tid = blockIdx.x * 256 + threadIdx.x;
    if (tid < 384 * 512) {
        int n = tid >> 9, k = tid & 511;
        float v = (n < 64)  ? Wf[k * 64 + n]
                : (n < 128) ? Wg[k * 64 + (n - 64)]
                            : Wh[k * 256 + (n - 128)];
        WcatT[tid] = f2bf(v);
    } else {
        int t2 = tid - 384 * 512;      // < 512*256
        int n = t2 >> 8, k = t2 & 255;
        WoT[t2] = f2bf(Wo[k * 512 + n]);
    }
}

// ---------------------------------------------------------------------------
// Kernel 1: qkv GEMM, double-buffered LDS + register prefetch, 1 barrier/iter.
// g pre-scaled by log2(e).
// ---------------------------------------------------------------------------
__global__ __launch_bounds__(256, 2) void qkv_mfma(
    const float* __restrict__ x, const short* __restrict__ WcatT,
    const float* __restrict__ bfv, const float* __restrict__ bgv,
    const float* __restrict__ bhv,
    short* __restrict__ fbf, short* __restrict__ gbf, short* __restrict__ hT)
{
    const int ny = blockIdx.x;           // 0..2
    const int m0 = blockIdx.y * 128;
    const int n0 = ny * 128;
    const int t  = threadIdx.x;
    const int w  = t >> 6, lane = t & 63;
    const int l15 = lane & 15, quad = lane >> 4;
    const int wm = w & 1, wn = w >> 1;

    __shared__ short As[2][128 * 40];
    __shared__ short Bs[2][128 * 40];

    const int a_row = t >> 1, a_ko = (t & 1) * 16;   // 2 float4 each (16 k)
    const int b_row = t >> 1, b_ko = (t & 1) * 16;   // 2 bf16x8 each

    floatx4 acc[4][4];
    #pragma unroll
    for (int i = 0; i < 4; i++)
        #pragma unroll
        for (int j = 0; j < 4; j++) acc[i][j] = (floatx4){0.f,0.f,0.f,0.f};

    // prologue: load + commit tile 0
    float4 av[4]; bf16x8 bv[2];
    #pragma unroll
    for (int i = 0; i < 4; i++)
        av[i] = *(const float4*)&x[(size_t)(m0 + a_row) * C_ + a_ko + i * 4];
    #pragma unroll
    for (int i = 0; i < 2; i++)
        bv[i] = *(const bf16x8*)&WcatT[(size_t)(n0 + b_row) * 512 + b_ko + i * 8];
    #pragma unroll
    for (int i = 0; i < 4; i++) {
        bf16x4 pk = { f2bf(av[i].x), f2bf(av[i].y), f2bf(av[i].z), f2bf(av[i].w) };
        *(bf16x4*)&As[0][a_row * 40 + a_ko + i * 4] = pk;
    }
    #pragma unroll
    for (int i = 0; i < 2; i++)
        *(bf16x8*)&Bs[0][b_row * 40 + b_ko + i * 8] = bv[i];

    for (int it = 0; it < 16; ++it) {
        const int cur = it & 1;
        const bool more = (it < 15);
        const int kn = (it + 1) * 32;
        __syncthreads();

        if (more) {
            #pragma unroll
            for (int i = 0; i < 4; i++)
                av[i] = *(const float4*)&x[(size_t)(m0 + a_row) * C_ + kn + a_ko + i * 4];
            #pragma unroll
            for (int i = 0; i < 2; i++)
                bv[i] = *(const bf16x8*)&WcatT[(size_t)(n0 + b_row) * 512 + kn + b_ko + i * 8];
        }

        bf16x8 af[4], bfr[4];
        #pragma unroll
        for (int mt = 0; mt < 4; mt++)
            af[mt] = *(const bf16x8*)&As[cur][(wm * 64 + mt * 16 + l15) * 40 + quad * 8];
        #pragma unroll
        for (int nt = 0; nt < 4; nt++)
            bfr[nt] = *(const bf16x8*)&Bs[cur][(wn * 64 + nt * 16 + l15) * 40 + quad * 8];
        #pragma unroll
        for (int mt = 0; mt < 4; mt++)
            #pragma unroll
            for (int nt = 0; nt < 4; nt++)
                acc[mt][nt] = __builtin_amdgcn_mfma_f32_16x16x32_bf16(af[mt], bfr[nt], acc[mt][nt], 0, 0, 0);

        if (more) {
            const int nxt = cur ^ 1;
            #pragma unroll
            for (int i = 0; i < 4; i++) {
                bf16x4 pk = { f2bf(av[i].x), f2bf(av[i].y), f2bf(av[i].z), f2bf(av[i].w) };
                *(bf16x4*)&As[nxt][a_row * 40 + a_ko + i * 4] = pk;
            }
            #pragma unroll
            for (int i = 0; i < 2; i++)
                *(bf16x8*)&Bs[nxt][b_row * 40 + b_ko + i * 8] = bv[i];
        }
    }

    if (ny == 0) {
        #pragma unroll
        for (int mt = 0; mt < 4; mt++) {
            #pragma unroll
            for (int nt = 0; nt < 4; nt++) {
                int cn = wn * 64 + nt * 16 + l15;
                #pragma unroll
                for (int rg = 0; rg < 4; rg++) {
                    int row = m0 + wm * 64 + mt * 16 + quad * 4 + rg;
                    float v = acc[mt][nt][rg];
                    if (cn < 64) fbf[(size_t)row * 64 + cn]        = f2bf(v + bfv[cn]);
                    else         gbf[(size_t)row * 64 + (cn - 64)] = f2bf((v + bgv[cn - 64]) * LOG2E);
                }
            }
        }
    } else {
        #pragma unroll
        for (int mt = 0; mt < 4; mt++) {
            #pragma unroll
            for (int nt = 0; nt < 4; nt++) {
                int hch = (ny - 1) * 128 + wn * 64 + nt * 16 + l15;
                int row = m0 + wm * 64 + mt * 16 + quad * 4;
                int bb = row >> 12, n = row & 4095;
                float bias = bhv[hch];
                bf16x4 pk = { f2bf(acc[mt][nt][0] + bias), f2bf(acc[mt][nt][1] + bias),
                              f2bf(acc[mt][nt][2] + bias), f2bf(acc[mt][nt][3] + bias) };
                *(bf16x4*)&hT[((size_t)(bb * 256 + hch)) * 4096 + n] = pk;
            }
        }
    }
}

// ---------------------------------------------------------------------------
// Kernel 2: attention v6.  Block = 128 q x 128 vch (vch-split 2, kv-split 2).
// 2 blocks/CU (LB(256,2)), no reg prefetch (stage-at-top, 2 barriers/iter).
// Wave: wq (64 q), wv (64 vch). oacc 64 regs/wave -> no spill.
// ---------------------------------------------------------------------------
#define HST 40

__global__ __launch_bounds__(256, 2) void attn_v6(
    const short* __restrict__ fK,    // keys    [B*N,64]
    const short* __restrict__ gQ,    // queries [B*N,64] (pre-scaled by log2e)
    const short* __restrict__ hT,    // values  [B,256,4096]
    short* __restrict__ oPartB,      // [2][B*N,256] bf16
    float* __restrict__ lPart)       // [2][B*N]
{
    const int bx = blockIdx.x;
    const int s  = bx & 1;
    const int vs = (bx >> 1) & 1;
    const int qt = (bx >> 2) & 31;
    const int b  = bx >> 7;
    const int kb = s * 2048;
    const int t  = threadIdx.x;
    const int w  = t >> 6, lane = t & 63;
    const int l31 = lane & 31, h = lane >> 5;
    const int wq = w & 1, wv = w >> 1;
    const int q_wave = qt * 128 + wq * 64;
    const int v_wave = vs * 128 + wv * 64;   // global vch base for this wave

    __shared__ short fs[2][64 * HST];    // keys  [key][d]
    __shared__ short hs[2][128 * HST];   // V^T   [vch_local][key]

    // Q B-frags (B[k=d][n=q]: n=l31, k=16k+8h+j)
    bf16x8 qf[2][4];
    #pragma unroll
    for (int n2 = 0; n2 < 2; n2++)
        #pragma unroll
        for (int k = 0; k < 4; k++)
            qf[n2][k] = *(const bf16x8*)&gQ[(size_t)(b * N_ + q_wave + n2 * 32 + l31) * 64 + k * 16 + h * 8];

    floatx16 oacc[2][2];   // [n2][vt]
    #pragma unroll
    for (int n2 = 0; n2 < 2; n2++)
        #pragma unroll
        for (int vt = 0; vt < 2; vt++)
            #pragma unroll
            for (int j = 0; j < 16; j++) oacc[n2][vt][j] = 0.f;
    float lsum[2] = {0.f, 0.f};

    const int f_row = t >> 2, f_c = (t & 3) * 16;   // fs: 2 b128
    const int h_row = t >> 3, h_c = (t & 7) * 8;    // hs: rows h_row + 32*i, i<4

    // prologue: stage tile 0
    {
        *(bf16x8*)&fs[0][f_row * HST + f_c] =
            *(const bf16x8*)&fK[(size_t)(b * N_ + kb + f_row) * 64 + f_c];
        *(bf16x8*)&fs[0][f_row * HST + f_c + 8] =
            *(const bf16x8*)&fK[(size_t)(b * N_ + kb + f_row) * 64 + f_c + 8];
        #pragma unroll
        for (int i = 0; i < 4; i++)
            *(bf16x8*)&hs[0][(h_row + i * 32) * HST + h_c] =
                *(const bf16x8*)&hT[((size_t)(b * 256 + vs * 128 + h_row + i * 32)) * 4096 + kb + h_c];
    }

    for (int it = 0; it < 32; ++it) {
        const int cur = it & 1;
        const int nxt = cur ^ 1;
        const bool more = (it < 31);
        const int kn = kb + (it + 1) * 64;

        // stage next tile into nxt (prev compute on nxt finished: barrier below
        // at end of prior iter); then barrier; then compute cur.
        if (more) {
            *(bf16x8*)&fs[nxt][f_row * HST + f_c] =
                *(const bf16x8*)&fK[(size_t)(b * N_ + kn + f_row) * 64 + f_c];
            *(bf16x8*)&fs[nxt][f_row * HST + f_c + 8] =
                *(const bf16x8*)&fK[(size_t)(b * N_ + kn + f_row) * 64 + f_c + 8];
            #pragma unroll
            for (int i = 0; i < 4; i++)
                *(bf16x8*)&hs[nxt][(h_row + i * 32) * HST + h_c] =
                    *(const bf16x8*)&hT[((size_t)(b * 256 + vs * 128 + h_row + i * 32)) * 4096 + kn + h_c];
        }
        __syncthreads();

        #pragma unroll
        for (int m = 0; m < 2; m++) {
            // ---- S^T = F @ Q^T for key half m (32 keys) ----
            bf16x8 ffr[4];
            #pragma unroll
            for (int k = 0; k < 4; k++)
                ffr[k] = *(const bf16x8*)&fs[cur][(m * 32 + l31) * HST + k * 16 + h * 8];

            floatx16 sacc[2];
            #pragma unroll
            for (int n2 = 0; n2 < 2; n2++)
                #pragma unroll
                for (int j = 0; j < 16; j++) sacc[n2][j] = 0.f;
            #pragma unroll
            for (int k = 0; k < 4; k++)
                #pragma unroll
                for (int n2 = 0; n2 < 2; n2++)
                    sacc[n2] = __builtin_amdgcn_mfma_f32_32x32x16_bf16(
                        ffr[k], qf[n2][k], sacc[n2], 0, 0, 0);

            // ---- exp2 + in-register transpose to PV A-frags ----
            bf16x8 pf[2][2];    // [n2][kp]
            #pragma unroll
            for (int n2 = 0; n2 < 2; n2++) {
                float p[16]; float ps_ = 0.f;
                #pragma unroll
                for (int j = 0; j < 16; j++) { p[j] = exp2f(sacc[n2][j]); ps_ += p[j]; }
                ps_ += __shfl_xor(ps_, 32);
                lsum[n2] += ps_;
                unsigned pk[8], xk[8];
                #pragma unroll
                for (int i = 0; i < 8; i++) pk[i] = pack2bf_fast(p[2 * i], p[2 * i + 1]);
                #pragma unroll
                for (int i = 0; i < 8; i++) xk[i] = __shfl_xor(pk[i], 32);
                #pragma unroll
                for (int kp = 0; kp < 2; kp++) {
                    U8 u;
                    u.u[0] = h ? xk[4 * kp + 2] : pk[4 * kp];
                    u.u[1] = h ? xk[4 * kp + 3] : pk[4 * kp + 1];
                    u.u[2] = h ? pk[4 * kp + 2] : xk[4 * kp];
                    u.u[3] = h ? pk[4 * kp + 3] : xk[4 * kp + 1];
                    pf[n2][kp] = u.v;
                }
            }

            // ---- O += P @ V for this key half (wave's 64 vch) ----
            #pragma unroll
            for (int kp = 0; kp < 2; kp++) {
                const int kk = m * 2 + kp;
                #pragma unroll
                for (int vt = 0; vt < 2; vt++) {
                    bf16x8 vfr = *(const bf16x8*)&hs[cur][(wv * 64 + vt * 32 + l31) * HST + kk * 16 + h * 8];
                    #pragma unroll
                    for (int n2 = 0; n2 < 2; n2++)
                        oacc[n2][vt] = __builtin_amdgcn_mfma_f32_32x32x16_bf16(
                            pf[n2][kp], vfr, oacc[n2][vt], 0, 0, 0);
                }
            }
        }
        __syncthreads();
    }

    // ---- epilogue: store partial O (bf16) and partial l ----
    #pragma unroll
    for (int n2 = 0; n2 < 2; n2++) {
        #pragma unroll
        for (int vt = 0; vt < 2; vt++) {
            int vch = v_wave + vt * 32 + l31;
            #pragma unroll
            for (int r = 0; r < 16; r++) {
                int q = q_wave + n2 * 32 + (r & 3) + 8 * (r >> 2) + 4 * h;
                oPartB[(size_t)s * 4194304 + (size_t)(b * N_ + q) * 256 + vch] = f2bf(oacc[n2][vt][r]);
            }
        }
    }
    if (vs == 0 && wv == 0 && lane < 32) {
        #pragma unroll
        for (int n2 = 0; n2 < 2; n2++)
            lPart[(size_t)s * 16384 + b * N_ + q_wave + n2 * 32 + lane] = lsum[n2];
    }
}

// ---------------------------------------------------------------------------
// Kernel 2b: combine kv-splits: obf = (O0+O1)/(l0+l1), bf16.
// ---------------------------------------------------------------------------
__global__ __launch_bounds__(256) void attn_combine(
    const short* __restrict__ oPartB, const float* __restrict__ lPart,
    short* __restrict__ obf)
{
    int idx = blockIdx.x * 256 + threadIdx.x;     // 512K threads, 8 ch each
    int row = idx >> 5;
    int c8  = (idx & 31) << 3;
    bf16x8 v0 = *(const bf16x8*)&oPartB[(size_t)row * 256 + c8];
    bf16x8 v1 = *(const bf16x8*)&oPartB[4194304 + (size_t)row * 256 + c8];
    float inv = 1.0f / (lPart[row] + lPart[16384 + row]);
    bf16x8 o;
    #pragma unroll
    for (int j = 0; j < 8; j++) o[j] = f2bf((bf2f(v0[j]) + bf2f(v1[j])) * inv);
    *(bf16x8*)&obf[(size_t)row * 256 + c8] = o;
}

// ---------------------------------------------------------------------------
// Kernel 3: out = gamma*(o @ Wo + bo) + x, double-buffered + reg prefetch.
// ---------------------------------------------------------------------------
__global__ __launch_bounds__(256, 2) void out_mfma(
    const short* __restrict__ obf, const short* __restrict__ WoT,
    const float* __restrict__ bo, const float* __restrict__ x,
    const float* __restrict__ gamma, float* __restrict__ out)
{
    const int n0 = blockIdx.x * 128;
    const int m0 = blockIdx.y * 128;
    const int t  = threadIdx.x;
    const int w  = t >> 6, lane = t & 63;
    const int l15 = lane & 15, quad = lane >> 4;
    const int wm = w & 1, wn = w >> 1;

    __shared__ short As[2][128 * 40];
    __shared__ short Bs[2][128 * 40];

    const int r_row = t >> 1, r_ko = (t & 1) * 16;   // 2 bf16x8 each

    floatx4 acc[4][4];
    #pragma unroll
    for (int i = 0; i < 4; i++)
        #pragma unroll
        for (int j = 0; j < 4; j++) acc[i][j] = (floatx4){0.f,0.f,0.f,0.f};

    bf16x8 avv[2], bvv[2];
    #pragma unroll
    for (int i = 0; i < 2; i++) {
        avv[i] = *(const bf16x8*)&obf[(size_t)(m0 + r_row) * 256 + r_ko + i * 8];
        bvv[i] = *(const bf16x8*)&WoT[(size_t)(n0 + r_row) * 256 + r_ko + i * 8];
    }
    #pragma unroll
    for (int i = 0; i < 2; i++) {
        *(bf16x8*)&As[0][r_row * 40 + r_ko + i * 8] = avv[i];
        *(bf16x8*)&Bs[0][r_row * 40 + r_ko + i * 8] = bvv[i];
    }

    for (int it = 0; it < 8; ++it) {
        const int cur = it & 1;
        const bool more = (it < 7);
        const int kn = (it + 1) * 32;
        __syncthreads();

        if (more) {
            #pragma unroll
            for (int i = 0; i < 2; i++) {
                avv[i] = *(const bf16x8*)&obf[(size_t)(m0 + r_row) * 256 + kn + r_ko + i * 8];
                bvv[i] = *(const bf16x8*)&WoT[(size_t)(n0 + r_row) * 256 + kn + r_ko + i * 8];
            }
        }

        bf16x8 af[4], bfr[4];
        #pragma unroll
        for (int mt = 0; mt < 4; mt++)
            af[mt] = *(const bf16x8*)&As[cur][(wm * 64 + mt * 16 + l15) * 40 + quad * 8];
        #pragma unroll
        for (int nt = 0; nt < 4; nt++)
            bfr[nt] = *(const bf16x8*)&Bs[cur][(wn * 64 + nt * 16 + l15) * 40 + quad * 8];
        #pragma unroll
        for (int mt = 0; mt < 4; mt++)
            #pragma unroll
            for (int nt = 0; nt < 4; nt++)
                acc[mt][nt] = __builtin_amdgcn_mfma_f32_16x16x32_bf16(af[mt], bfr[nt], acc[mt][nt], 0, 0, 0);

        if (more) {
            const int nxt = cur ^ 1;
            #pragma unroll
            for (int i = 0; i < 2; i++) {
                *(bf16x8*)&As[nxt][r_row * 40 + r_ko + i * 8] = avv[i];
                *(bf16x8*)&Bs[nxt][r_row * 40 + r_ko + i * 8] = bvv[i];
            }
        }
    }

    const float gm = gamma[0];
    #pragma unroll
    for (int mt = 0; mt < 4; mt++) {
        #pragma unroll
        for (int nt = 0; nt < 4; nt++) {
            int col = n0 + wn * 64 + nt * 16 + l15;
            float bias = bo[col];
            #pragma unroll
            for (int rg = 0; rg < 4; rg++) {
                int row = m0 + wm * 64 + mt * 16 + quad * 4 + rg;
                out[(size_t)row * C_ + col] =
                    gm * (acc[mt][nt][rg] + bias) + x[(size_t)row * C_ + col];
            }
        }
    }
}

// ---------------------------------------------------------------------------
extern "C" void kernel_launch(void* const* d_in, const int* in_sizes, int n_in,
                              void* d_out, int out_size, void* d_ws, size_t ws_size,
                              hipStream_t stream) {
    (void)in_sizes; (void)n_in; (void)out_size; (void)ws_size;

    const float* x     = (const float*)d_in[0];
    const float* Wf    = (const float*)d_in[1];
    const float* bfv   = (const float*)d_in[2];
    const float* Wg    = (const float*)d_in[3];
    const float* bgv   = (const float*)d_in[4];
    const float* Wh    = (const float*)d_in[5];
    const float* bhv   = (const float*)d_in[6];
    const float* Wo    = (const float*)d_in[7];
    const float* bo    = (const float*)d_in[8];
    const float* gamma = (const float*)d_in[9];
    float* out = (float*)d_out;

    short* fbf    = (short*)d_ws;
    short* gbf    = fbf    + (size_t)B_ * N_ * C8_;
    short* hT     = gbf    + (size_t)B_ * N_ * C8_;
    short* obf    = hT     + (size_t)B_ * C2_ * N_;
    short* WcatT  = obf    + (size_t)B_ * N_ * C2_;
    short* WoT    = WcatT  + (size_t)384 * 512;
    short* oPartB = WoT    + (size_t)512 * 256;
    float* lPart  = (float*)(oPartB + (size_t)2 * 16384 * 256);

    convert_w<<<1280, 256, 0, stream>>>(Wf, Wg, Wh, Wo, WcatT, WoT);
    qkv_mfma<<<dim3(3, 128), 256, 0, stream>>>(x, WcatT, bfv, bgv, bhv, fbf, gbf, hT);
    attn_v6<<<512, 256, 0, stream>>>(fbf, gbf, hT, oPartB, lPart);
    attn_combine<<<2048, 256, 0, stream>>>(oPartB, lPart, obf);
    out_mfma<<<dim3(4, 128), 256, 0, stream>>>(obf, WoT, bo, x, gamma, out);
}

// Round 7
// 263.377 us; speedup vs baseline: 1.0693x; 1.0693x over previous
//
#include <hip/hip_runtime.h>
#include <math.h>

#define B_   4
#define N_   4096
#define C_   512
#define C8_  64
#define C2_  256
#define LOG2E 1.44269504f

typedef __attribute__((ext_vector_type(8))) short bf16x8;
typedef __attribute__((ext_vector_type(4))) short bf16x4;
typedef __attribute__((ext_vector_type(4))) float floatx4;
typedef __attribute__((ext_vector_type(16))) float floatx16;

__device__ __forceinline__ short f2bf(float x) {
    unsigned u = __float_as_uint(x);
    u += 0x7fff + ((u >> 16) & 1);          // round-to-nearest-even
    return (short)(u >> 16);
}
// (bf(a) | bf(b)<<16) round-half-up: 2 adds + 1 v_perm
__device__ __forceinline__ unsigned pack2bf_fast(float a, float b) {
    unsigned ua = __float_as_uint(a) + 0x8000u;
    unsigned ub = __float_as_uint(b) + 0x8000u;
    return __builtin_amdgcn_perm(ub, ua, 0x07060302u);
}
__device__ __forceinline__ float bf2f(short s) {
    return __uint_as_float(((unsigned)(unsigned short)s) << 16);
}
// async global->LDS, 16B per lane. LDS dest = base + lane*16 (wave-uniform base).
__device__ __forceinline__ void gl_lds16(const void* g, void* l) {
    __builtin_amdgcn_global_load_lds(
        (const __attribute__((address_space(1))) unsigned int*)g,
        (__attribute__((address_space(3))) unsigned int*)l, 16, 0, 0);
}

union U8 { bf16x8 v; unsigned u[4]; };

// ---------------------------------------------------------------------------
// Kernel 0: weight prep + lTot zeroing.
// ---------------------------------------------------------------------------
__global__ __launch_bounds__(256) void convert_w(
    const float* __restrict__ Wf, const float* __restrict__ Wg,
    const float* __restrict__ Wh, const float* __restrict__ Wo,
    short* __restrict__ WcatT, short* __restrict__ WoT,
    float* __restrict__ lTot)
{
    int tid = blockIdx.x * 256 + threadIdx.x;
    if (tid < 16384) lTot[tid] = 0.f;
    if (tid < 384 * 512) {
        int n = tid >> 9, k = tid & 511;
        float v = (n < 64)  ? Wf[k * 64 + n]
                : (n < 128) ? Wg[k * 64 + (n - 64)]
                            : Wh[k * 256 + (n - 128)];
        WcatT[tid] = f2bf(v);
    } else {
        int t2 = tid - 384 * 512;      // < 512*256
        int n = t2 >> 8, k = t2 & 255;
        WoT[t2] = f2bf(Wo[k * 512 + n]);
    }
}

// ---------------------------------------------------------------------------
// Kernel 1: qkv GEMM, double-buffered LDS + register prefetch, 1 barrier/iter.
// g pre-scaled by log2(e).
// ---------------------------------------------------------------------------
__global__ __launch_bounds__(256, 2) void qkv_mfma(
    const float* __restrict__ x, const short* __restrict__ WcatT,
    const float* __restrict__ bfv, const float* __restrict__ bgv,
    const float* __restrict__ bhv,
    short* __restrict__ fbf, short* __restrict__ gbf, short* __restrict__ hT)
{
    const int ny = blockIdx.x;           // 0..2
    const int m0 = blockIdx.y * 128;
    const int n0 = ny * 128;
    const int t  = threadIdx.x;
    const int w  = t >> 6, lane = t & 63;
    const int l15 = lane & 15, quad = lane >> 4;
    const int wm = w & 1, wn = w >> 1;

    __shared__ short As[2][128 * 40];
    __shared__ short Bs[2][128 * 40];

    const int a_row = t >> 1, a_ko = (t & 1) * 16;
    const int b_row = t >> 1, b_ko = (t & 1) * 16;

    floatx4 acc[4][4];
    #pragma unroll
    for (int i = 0; i < 4; i++)
        #pragma unroll
        for (int j = 0; j < 4; j++) acc[i][j] = (floatx4){0.f,0.f,0.f,0.f};

    float4 av[4]; bf16x8 bv[2];
    #pragma unroll
    for (int i = 0; i < 4; i++)
        av[i] = *(const float4*)&x[(size_t)(m0 + a_row) * C_ + a_ko + i * 4];
    #pragma unroll
    for (int i = 0; i < 2; i++)
        bv[i] = *(const bf16x8*)&WcatT[(size_t)(n0 + b_row) * 512 + b_ko + i * 8];
    #pragma unroll
    for (int i = 0; i < 4; i++) {
        bf16x4 pk = { f2bf(av[i].x), f2bf(av[i].y), f2bf(av[i].z), f2bf(av[i].w) };
        *(bf16x4*)&As[0][a_row * 40 + a_ko + i * 4] = pk;
    }
    #pragma unroll
    for (int i = 0; i < 2; i++)
        *(bf16x8*)&Bs[0][b_row * 40 + b_ko + i * 8] = bv[i];

    for (int it = 0; it < 16; ++it) {
        const int cur = it & 1;
        const bool more = (it < 15);
        const int kn = (it + 1) * 32;
        __syncthreads();

        if (more) {
            #pragma unroll
            for (int i = 0; i < 4; i++)
                av[i] = *(const float4*)&x[(size_t)(m0 + a_row) * C_ + kn + a_ko + i * 4];
            #pragma unroll
            for (int i = 0; i < 2; i++)
                bv[i] = *(const bf16x8*)&WcatT[(size_t)(n0 + b_row) * 512 + kn + b_ko + i * 8];
        }

        bf16x8 af[4], bfr[4];
        #pragma unroll
        for (int mt = 0; mt < 4; mt++)
            af[mt] = *(const bf16x8*)&As[cur][(wm * 64 + mt * 16 + l15) * 40 + quad * 8];
        #pragma unroll
        for (int nt = 0; nt < 4; nt++)
            bfr[nt] = *(const bf16x8*)&Bs[cur][(wn * 64 + nt * 16 + l15) * 40 + quad * 8];
        #pragma unroll
        for (int mt = 0; mt < 4; mt++)
            #pragma unroll
            for (int nt = 0; nt < 4; nt++)
                acc[mt][nt] = __builtin_amdgcn_mfma_f32_16x16x32_bf16(af[mt], bfr[nt], acc[mt][nt], 0, 0, 0);

        if (more) {
            const int nxt = cur ^ 1;
            #pragma unroll
            for (int i = 0; i < 4; i++) {
                bf16x4 pk = { f2bf(av[i].x), f2bf(av[i].y), f2bf(av[i].z), f2bf(av[i].w) };
                *(bf16x4*)&As[nxt][a_row * 40 + a_ko + i * 4] = pk;
            }
            #pragma unroll
            for (int i = 0; i < 2; i++)
                *(bf16x8*)&Bs[nxt][b_row * 40 + b_ko + i * 8] = bv[i];
        }
    }

    if (ny == 0) {
        #pragma unroll
        for (int mt = 0; mt < 4; mt++) {
            #pragma unroll
            for (int nt = 0; nt < 4; nt++) {
                int cn = wn * 64 + nt * 16 + l15;
                #pragma unroll
                for (int rg = 0; rg < 4; rg++) {
                    int row = m0 + wm * 64 + mt * 16 + quad * 4 + rg;
                    float v = acc[mt][nt][rg];
                    if (cn < 64) fbf[(size_t)row * 64 + cn]        = f2bf(v + bfv[cn]);
                    else         gbf[(size_t)row * 64 + (cn - 64)] = f2bf((v + bgv[cn - 64]) * LOG2E);
                }
            }
        }
    } else {
        #pragma unroll
        for (int mt = 0; mt < 4; mt++) {
            #pragma unroll
            for (int nt = 0; nt < 4; nt++) {
                int hch = (ny - 1) * 128 + wn * 64 + nt * 16 + l15;
                int row = m0 + wm * 64 + mt * 16 + quad * 4;
                int bb = row >> 12, n = row & 4095;
                float bias = bhv[hch];
                bf16x4 pk = { f2bf(acc[mt][nt][0] + bias), f2bf(acc[mt][nt][1] + bias),
                              f2bf(acc[mt][nt][2] + bias), f2bf(acc[mt][nt][3] + bias) };
                *(bf16x4*)&hT[((size_t)(bb * 256 + hch)) * 4096 + n] = pk;
            }
        }
    }
}

// ---------------------------------------------------------------------------
// Kernel 2: attention v7.  Wave = 64 q x 128 vch (R4 layout), m-split softmax,
// global_load_lds staging with XOR chunk swizzle (rows unpadded 128B),
// kv-split 4, 2 blocks/CU. Unnormalized softmax; l via global float atomics.
// LDS rows: 64 shorts; logical 16B-chunk kc stored at phys chunk kc^(row&7).
// ---------------------------------------------------------------------------
__global__ __launch_bounds__(256, 2) void attn_v7(
    const short* __restrict__ fK,    // keys    [B*N,64]
    const short* __restrict__ gQ,    // queries [B*N,64] (pre-scaled by log2e)
    const short* __restrict__ hT,    // values  [B,256,4096]
    short* __restrict__ oPartB,      // [4][B*N,256] bf16
    float* __restrict__ lTot)        // [B*N] (pre-zeroed; atomic-accumulated)
{
    const int bx = blockIdx.x;
    const int s  = bx & 3;
    const int qt = (bx >> 2) & 31;
    const int b  = bx >> 7;
    const int kb = s * 1024;
    const int t  = threadIdx.x;
    const int w  = t >> 6, lane = t & 63;
    const int l31 = lane & 31, h = lane >> 5;
    const int wq = w & 1, wv = w >> 1;
    const int q_wave = qt * 128 + wq * 64;

    __shared__ short fs[2][64 * 64];     // keys  [key][d]  (swizzled chunks)
    __shared__ short hs[2][256 * 64];    // V^T   [vch][key] (swizzled chunks)

    // per-lane staging geometry for global_load_lds
    const int wr = lane >> 3;                 // row within 8-row group
    const int kc = (lane & 7) ^ (wr & 7);     // logical key-chunk this lane fetches
    const int swz = l31 & 7;                  // read-side swizzle term

    // Q B-frags (B[k=d][n=q]: n=l31, k=16k+8h+j)
    bf16x8 qf[2][4];
    #pragma unroll
    for (int n2 = 0; n2 < 2; n2++)
        #pragma unroll
        for (int k = 0; k < 4; k++)
            qf[n2][k] = *(const bf16x8*)&gQ[(size_t)(b * N_ + q_wave + n2 * 32 + l31) * 64 + k * 16 + h * 8];

    floatx16 oacc[2][4];   // [n2][vt]: 64 q x 128 vch
    #pragma unroll
    for (int n2 = 0; n2 < 2; n2++)
        #pragma unroll
        for (int vt = 0; vt < 4; vt++)
            #pragma unroll
            for (int j = 0; j < 16; j++) oacc[n2][vt][j] = 0.f;
    float lsum[2] = {0.f, 0.f};

    // prologue: stage tile 0 (async) then barrier
    {
        #pragma unroll
        for (int j = 0; j < 2; j++) {
            int cc = w * 2 + j;
            int r = cc * 8 + wr;
            gl_lds16(&fK[(size_t)(b * N_ + kb + r) * 64 + kc * 8], &fs[0][cc * 512]);
        }
        #pragma unroll
        for (int j = 0; j < 8; j++) {
            int cc = w * 8 + j;
            int r = cc * 8 + wr;
            gl_lds16(&hT[((size_t)(b * 256 + r)) * 4096 + kb + kc * 8], &hs[0][cc * 512]);
        }
    }
    __syncthreads();

    for (int it = 0; it < 16; ++it) {
        const int cur = it & 1;
        const int nxt = cur ^ 1;
        const bool more = (it < 15);
        const int kn = kb + (it + 1) * 64;

        // issue async staging for next tile (drained by end-of-iter barrier)
        if (more) {
            #pragma unroll
            for (int j = 0; j < 2; j++) {
                int cc = w * 2 + j;
                int r = cc * 8 + wr;
                gl_lds16(&fK[(size_t)(b * N_ + kn + r) * 64 + kc * 8], &fs[nxt][cc * 512]);
            }
            #pragma unroll
            for (int j = 0; j < 8; j++) {
                int cc = w * 8 + j;
                int r = cc * 8 + wr;
                gl_lds16(&hT[((size_t)(b * 256 + r)) * 4096 + kn + kc * 8], &hs[nxt][cc * 512]);
            }
        }

        #pragma unroll
        for (int m = 0; m < 2; m++) {
            // ---- S^T = F @ Q^T for key half m (32 keys) ----
            bf16x8 ffr[4];
            #pragma unroll
            for (int k = 0; k < 4; k++)
                ffr[k] = *(const bf16x8*)&fs[cur][(m * 32 + l31) * 64 + (((2 * k + h) ^ swz) * 8)];

            floatx16 sacc[2];
            #pragma unroll
            for (int n2 = 0; n2 < 2; n2++)
                #pragma unroll
                for (int j = 0; j < 16; j++) sacc[n2][j] = 0.f;
            #pragma unroll
            for (int k = 0; k < 4; k++)
                #pragma unroll
                for (int n2 = 0; n2 < 2; n2++)
                    sacc[n2] = __builtin_amdgcn_mfma_f32_32x32x16_bf16(
                        ffr[k], qf[n2][k], sacc[n2], 0, 0, 0);

            // ---- exp2 + in-register transpose to PV A-frags ----
            bf16x8 pf[2][2];    // [n2][kp]
            #pragma unroll
            for (int n2 = 0; n2 < 2; n2++) {
                float p[16]; float ps_ = 0.f;
                #pragma unroll
                for (int j = 0; j < 16; j++) { p[j] = exp2f(sacc[n2][j]); ps_ += p[j]; }
                ps_ += __shfl_xor(ps_, 32);
                lsum[n2] += ps_;
                unsigned pk[8], xk[8];
                #pragma unroll
                for (int i = 0; i < 8; i++) pk[i] = pack2bf_fast(p[2 * i], p[2 * i + 1]);
                #pragma unroll
                for (int i = 0; i < 8; i++) xk[i] = __shfl_xor(pk[i], 32);
                #pragma unroll
                for (int kp = 0; kp < 2; kp++) {
                    U8 u;
                    u.u[0] = h ? xk[4 * kp + 2] : pk[4 * kp];
                    u.u[1] = h ? xk[4 * kp + 3] : pk[4 * kp + 1];
                    u.u[2] = h ? pk[4 * kp + 2] : xk[4 * kp];
                    u.u[3] = h ? pk[4 * kp + 3] : xk[4 * kp + 1];
                    pf[n2][kp] = u.v;
                }
            }

            // ---- O += P @ V for this key half (wave's 128 vch) ----
            #pragma unroll
            for (int kp = 0; kp < 2; kp++) {
                const int kk = m * 2 + kp;
                #pragma unroll
                for (int vt = 0; vt < 4; vt++) {
                    bf16x8 vfr = *(const bf16x8*)&hs[cur][(wv * 128 + vt * 32 + l31) * 64 + (((2 * kk + h) ^ swz) * 8)];
                    #pragma unroll
                    for (int n2 = 0; n2 < 2; n2++)
                        oacc[n2][vt] = __builtin_amdgcn_mfma_f32_32x32x16_bf16(
                            pf[n2][kp], vfr, oacc[n2][vt], 0, 0, 0);
                }
            }
        }
        __syncthreads();   // drains vmcnt -> nxt tile ready
    }

    // ---- epilogue: store partial O (bf16); accumulate l atomically ----
    #pragma unroll
    for (int n2 = 0; n2 < 2; n2++) {
        #pragma unroll
        for (int vt = 0; vt < 4; vt++) {
            int vch = wv * 128 + vt * 32 + l31;
            #pragma unroll
            for (int r = 0; r < 16; r++) {
                int q = q_wave + n2 * 32 + (r & 3) + 8 * (r >> 2) + 4 * h;
                oPartB[(size_t)s * 4194304 + (size_t)(b * N_ + q) * 256 + vch] = f2bf(oacc[n2][vt][r]);
            }
        }
    }
    if (wv == 0 && lane < 32) {
        #pragma unroll
        for (int n2 = 0; n2 < 2; n2++)
            atomicAdd(&lTot[b * N_ + q_wave + n2 * 32 + lane], lsum[n2]);
    }
}

// ---------------------------------------------------------------------------
// Kernel 3: out = gamma*((sum_s O_s)/l @ Wo + bo) + x.  Combine fused into
// A-staging (sum 4 bf16 partials); 1/l applied per output row in epilogue.
// ---------------------------------------------------------------------------
__global__ __launch_bounds__(256, 2) void out_mfma(
    const short* __restrict__ oPartB, const float* __restrict__ lTot,
    const short* __restrict__ WoT,
    const float* __restrict__ bo, const float* __restrict__ x,
    const float* __restrict__ gamma, float* __restrict__ out)
{
    const int n0 = blockIdx.x * 128;
    const int m0 = blockIdx.y * 128;
    const int t  = threadIdx.x;
    const int w  = t >> 6, lane = t & 63;
    const int l15 = lane & 15, quad = lane >> 4;
    const int wm = w & 1, wn = w >> 1;

    __shared__ short As[2][128 * 40];
    __shared__ short Bs[2][128 * 40];

    const int r_row = t >> 1, r_ko = (t & 1) * 16;

    floatx4 acc[4][4];
    #pragma unroll
    for (int i = 0; i < 4; i++)
        #pragma unroll
        for (int j = 0; j < 4; j++) acc[i][j] = (floatx4){0.f,0.f,0.f,0.f};

    bf16x8 pp[2][4];   // raw partials for 2 chunks x 4 splits
    bf16x8 bvv[2];

    #pragma unroll
    for (int i = 0; i < 2; i++) {
        size_t base = (size_t)(m0 + r_row) * 256 + r_ko + i * 8;
        #pragma unroll
        for (int sp = 0; sp < 4; sp++)
            pp[i][sp] = *(const bf16x8*)&oPartB[base + (size_t)sp * 4194304];
        bvv[i] = *(const bf16x8*)&WoT[(size_t)(n0 + r_row) * 256 + r_ko + i * 8];
    }
    #pragma unroll
    for (int i = 0; i < 2; i++) {
        U8 u;
        #pragma unroll
        for (int jj = 0; jj < 4; jj++) {
            float e0 = bf2f(pp[i][0][2*jj])   + bf2f(pp[i][1][2*jj])
                     + bf2f(pp[i][2][2*jj])   + bf2f(pp[i][3][2*jj]);
            float e1 = bf2f(pp[i][0][2*jj+1]) + bf2f(pp[i][1][2*jj+1])
                     + bf2f(pp[i][2][2*jj+1]) + bf2f(pp[i][3][2*jj+1]);
            u.u[jj] = pack2bf_fast(e0, e1);
        }
        *(bf16x8*)&As[0][r_row * 40 + r_ko + i * 8] = u.v;
        *(bf16x8*)&Bs[0][r_row * 40 + r_ko + i * 8] = bvv[i];
    }

    for (int it = 0; it < 8; ++it) {
        const int cur = it & 1;
        const bool more = (it < 7);
        const int kn = (it + 1) * 32;
        __syncthreads();

        if (more) {
            #pragma unroll
            for (int i = 0; i < 2; i++) {
                size_t base = (size_t)(m0 + r_row) * 256 + kn + r_ko + i * 8;
                #pragma unroll
                for (int sp = 0; sp < 4; sp++)
                    pp[i][sp] = *(const bf16x8*)&oPartB[base + (size_t)sp * 4194304];
                bvv[i] = *(const bf16x8*)&WoT[(size_t)(n0 + r_row) * 256 + kn + r_ko + i * 8];
            }
        }

        bf16x8 af[4], bfr[4];
        #pragma unroll
        for (int mt = 0; mt < 4; mt++)
            af[mt] = *(const bf16x8*)&As[cur][(wm * 64 + mt * 16 + l15) * 40 + quad * 8];
        #pragma unroll
        for (int nt = 0; nt < 4; nt++)
            bfr[nt] = *(const bf16x8*)&Bs[cur][(wn * 64 + nt * 16 + l15) * 40 + quad * 8];
        #pragma unroll
        for (int mt = 0; mt < 4; mt++)
            #pragma unroll
            for (int nt = 0; nt < 4; nt++)
                acc[mt][nt] = __builtin_amdgcn_mfma_f32_16x16x32_bf16(af[mt], bfr[nt], acc[mt][nt], 0, 0, 0);

        if (more) {
            const int nxt = cur ^ 1;
            #pragma unroll
            for (int i = 0; i < 2; i++) {
                U8 u;
                #pragma unroll
                for (int jj = 0; jj < 4; jj++) {
                    float e0 = bf2f(pp[i][0][2*jj])   + bf2f(pp[i][1][2*jj])
                             + bf2f(pp[i][2][2*jj])   + bf2f(pp[i][3][2*jj]);
                    float e1 = bf2f(pp[i][0][2*jj+1]) + bf2f(pp[i][1][2*jj+1])
                             + bf2f(pp[i][2][2*jj+1]) + bf2f(pp[i][3][2*jj+1]);
                    u.u[jj] = pack2bf_fast(e0, e1);
                }
                *(bf16x8*)&As[nxt][r_row * 40 + r_ko + i * 8] = u.v;
                *(bf16x8*)&Bs[nxt][r_row * 40 + r_ko + i * 8] = bvv[i];
            }
        }
    }

    const float gm = gamma[0];
    #pragma unroll
    for (int mt = 0; mt < 4; mt++) {
        float inv[4];
        #pragma unroll
        for (int rg = 0; rg < 4; rg++)
            inv[rg] = 1.0f / lTot[m0 + wm * 64 + mt * 16 + quad * 4 + rg];
        #pragma unroll
        for (int nt = 0; nt < 4; nt++) {
            int col = n0 + wn * 64 + nt * 16 + l15;
            float bias = bo[col];
            #pragma unroll
            for (int rg = 0; rg < 4; rg++) {
                int row = m0 + wm * 64 + mt * 16 + quad * 4 + rg;
                out[(size_t)row * C_ + col] =
                    gm * (acc[mt][nt][rg] * inv[rg] + bias) + x[(size_t)row * C_ + col];
            }
        }
    }
}

// ---------------------------------------------------------------------------
extern "C" void kernel_launch(void* const* d_in, const int* in_sizes, int n_in,
                              void* d_out, int out_size, void* d_ws, size_t ws_size,
                              hipStream_t stream) {
    (void)in_sizes; (void)n_in; (void)out_size; (void)ws_size;

    const float* x     = (const float*)d_in[0];
    const float* Wf    = (const float*)d_in[1];
    const float* bfv   = (const float*)d_in[2];
    const float* Wg    = (const float*)d_in[3];
    const float* bgv   = (const float*)d_in[4];
    const float* Wh    = (const float*)d_in[5];
    const float* bhv   = (const float*)d_in[6];
    const float* Wo    = (const float*)d_in[7];
    const float* bo    = (const float*)d_in[8];
    const float* gamma = (const float*)d_in[9];
    float* out = (float*)d_out;

    // ws (shorts): fbf 1M | gbf 1M | hT 4M | WcatT 192K | WoT 128K |
    // oPartB 16.78M shorts | lTot 16K floats   (~46 MB total)
    short* fbf    = (short*)d_ws;
    short* gbf    = fbf    + (size_t)B_ * N_ * C8_;
    short* hT     = gbf    + (size_t)B_ * N_ * C8_;
    short* WcatT  = hT     + (size_t)B_ * C2_ * N_;
    short* WoT    = WcatT  + (size_t)384 * 512;
    short* oPartB = WoT    + (size_t)512 * 256;
    float* lTot   = (float*)(oPartB + (size_t)4 * 16384 * 256);

    convert_w<<<1280, 256, 0, stream>>>(Wf, Wg, Wh, Wo, WcatT, WoT, lTot);
    qkv_mfma<<<dim3(3, 128), 256, 0, stream>>>(x, WcatT, bfv, bgv, bhv, fbf, gbf, hT);
    attn_v7<<<512, 256, 0, stream>>>(fbf, gbf, hT, oPartB, lTot);
    out_mfma<<<dim3(4, 128), 256, 0, stream>>>(oPartB, lTot, WoT, bo, x, gamma, out);
}

// Round 8
// 258.546 us; speedup vs baseline: 1.0893x; 1.0187x over previous
//
#include <hip/hip_runtime.h>
#include <math.h>

#define B_   4
#define N_   4096
#define C_   512
#define C8_  64
#define C2_  256
#define LOG2E 1.44269504f

typedef __attribute__((ext_vector_type(8))) short bf16x8;
typedef __attribute__((ext_vector_type(4))) short bf16x4;
typedef __attribute__((ext_vector_type(4))) float floatx4;
typedef __attribute__((ext_vector_type(16))) float floatx16;

__device__ __forceinline__ short f2bf(float x) {
    unsigned u = __float_as_uint(x);
    u += 0x7fff + ((u >> 16) & 1);          // round-to-nearest-even
    return (short)(u >> 16);
}
// (bf(a) | bf(b)<<16) round-half-up: 2 adds + 1 v_perm
__device__ __forceinline__ unsigned pack2bf_fast(float a, float b) {
    unsigned ua = __float_as_uint(a) + 0x8000u;
    unsigned ub = __float_as_uint(b) + 0x8000u;
    return __builtin_amdgcn_perm(ub, ua, 0x07060302u);
}
__device__ __forceinline__ float bf2f(short s) {
    return __uint_as_float(((unsigned)(unsigned short)s) << 16);
}
// async global->LDS, 16B per lane. LDS dest = base + lane*16 (wave-uniform base).
__device__ __forceinline__ void gl_lds16(const void* g, void* l) {
    __builtin_amdgcn_global_load_lds(
        (const __attribute__((address_space(1))) unsigned int*)g,
        (__attribute__((address_space(3))) unsigned int*)l, 16, 0, 0);
}

union U8 { bf16x8 v; unsigned u[4]; };

// ---------------------------------------------------------------------------
// Kernel 0: weight prep + lTot zeroing.
// ---------------------------------------------------------------------------
__global__ __launch_bounds__(256) void convert_w(
    const float* __restrict__ Wf, const float* __restrict__ Wg,
    const float* __restrict__ Wh, const float* __restrict__ Wo,
    short* __restrict__ WcatT, short* __restrict__ WoT,
    float* __restrict__ lTot)
{
    int tid = blockIdx.x * 256 + threadIdx.x;
    if (tid < 16384) lTot[tid] = 0.f;
    if (tid < 384 * 512) {
        int n = tid >> 9, k = tid & 511;
        float v = (n < 64)  ? Wf[k * 64 + n]
                : (n < 128) ? Wg[k * 64 + (n - 64)]
                            : Wh[k * 256 + (n - 128)];
        WcatT[tid] = f2bf(v);
    } else {
        int t2 = tid - 384 * 512;      // < 512*256
        int n = t2 >> 8, k = t2 & 255;
        WoT[t2] = f2bf(Wo[k * 512 + n]);
    }
}

// ---------------------------------------------------------------------------
// Kernel 1: qkv GEMM, double-buffered LDS + register prefetch, 1 barrier/iter.
// g pre-scaled by log2(e).
// ---------------------------------------------------------------------------
__global__ __launch_bounds__(256, 2) void qkv_mfma(
    const float* __restrict__ x, const short* __restrict__ WcatT,
    const float* __restrict__ bfv, const float* __restrict__ bgv,
    const float* __restrict__ bhv,
    short* __restrict__ fbf, short* __restrict__ gbf, short* __restrict__ hT)
{
    const int ny = blockIdx.x;           // 0..2
    const int m0 = blockIdx.y * 128;
    const int n0 = ny * 128;
    const int t  = threadIdx.x;
    const int w  = t >> 6, lane = t & 63;
    const int l15 = lane & 15, quad = lane >> 4;
    const int wm = w & 1, wn = w >> 1;

    __shared__ short As[2][128 * 40];
    __shared__ short Bs[2][128 * 40];

    const int a_row = t >> 1, a_ko = (t & 1) * 16;
    const int b_row = t >> 1, b_ko = (t & 1) * 16;

    floatx4 acc[4][4];
    #pragma unroll
    for (int i = 0; i < 4; i++)
        #pragma unroll
        for (int j = 0; j < 4; j++) acc[i][j] = (floatx4){0.f,0.f,0.f,0.f};

    float4 av[4]; bf16x8 bv[2];
    #pragma unroll
    for (int i = 0; i < 4; i++)
        av[i] = *(const float4*)&x[(size_t)(m0 + a_row) * C_ + a_ko + i * 4];
    #pragma unroll
    for (int i = 0; i < 2; i++)
        bv[i] = *(const bf16x8*)&WcatT[(size_t)(n0 + b_row) * 512 + b_ko + i * 8];
    #pragma unroll
    for (int i = 0; i < 4; i++) {
        bf16x4 pk = { f2bf(av[i].x), f2bf(av[i].y), f2bf(av[i].z), f2bf(av[i].w) };
        *(bf16x4*)&As[0][a_row * 40 + a_ko + i * 4] = pk;
    }
    #pragma unroll
    for (int i = 0; i < 2; i++)
        *(bf16x8*)&Bs[0][b_row * 40 + b_ko + i * 8] = bv[i];

    for (int it = 0; it < 16; ++it) {
        const int cur = it & 1;
        const bool more = (it < 15);
        const int kn = (it + 1) * 32;
        __syncthreads();

        if (more) {
            #pragma unroll
            for (int i = 0; i < 4; i++)
                av[i] = *(const float4*)&x[(size_t)(m0 + a_row) * C_ + kn + a_ko + i * 4];
            #pragma unroll
            for (int i = 0; i < 2; i++)
                bv[i] = *(const bf16x8*)&WcatT[(size_t)(n0 + b_row) * 512 + kn + b_ko + i * 8];
        }

        bf16x8 af[4], bfr[4];
        #pragma unroll
        for (int mt = 0; mt < 4; mt++)
            af[mt] = *(const bf16x8*)&As[cur][(wm * 64 + mt * 16 + l15) * 40 + quad * 8];
        #pragma unroll
        for (int nt = 0; nt < 4; nt++)
            bfr[nt] = *(const bf16x8*)&Bs[cur][(wn * 64 + nt * 16 + l15) * 40 + quad * 8];
        #pragma unroll
        for (int mt = 0; mt < 4; mt++)
            #pragma unroll
            for (int nt = 0; nt < 4; nt++)
                acc[mt][nt] = __builtin_amdgcn_mfma_f32_16x16x32_bf16(af[mt], bfr[nt], acc[mt][nt], 0, 0, 0);

        if (more) {
            const int nxt = cur ^ 1;
            #pragma unroll
            for (int i = 0; i < 4; i++) {
                bf16x4 pk = { f2bf(av[i].x), f2bf(av[i].y), f2bf(av[i].z), f2bf(av[i].w) };
                *(bf16x4*)&As[nxt][a_row * 40 + a_ko + i * 4] = pk;
            }
            #pragma unroll
            for (int i = 0; i < 2; i++)
                *(bf16x8*)&Bs[nxt][b_row * 40 + b_ko + i * 8] = bv[i];
        }
    }

    if (ny == 0) {
        #pragma unroll
        for (int mt = 0; mt < 4; mt++) {
            #pragma unroll
            for (int nt = 0; nt < 4; nt++) {
                int cn = wn * 64 + nt * 16 + l15;
                #pragma unroll
                for (int rg = 0; rg < 4; rg++) {
                    int row = m0 + wm * 64 + mt * 16 + quad * 4 + rg;
                    float v = acc[mt][nt][rg];
                    if (cn < 64) fbf[(size_t)row * 64 + cn]        = f2bf(v + bfv[cn]);
                    else         gbf[(size_t)row * 64 + (cn - 64)] = f2bf((v + bgv[cn - 64]) * LOG2E);
                }
            }
        }
    } else {
        #pragma unroll
        for (int mt = 0; mt < 4; mt++) {
            #pragma unroll
            for (int nt = 0; nt < 4; nt++) {
                int hch = (ny - 1) * 128 + wn * 64 + nt * 16 + l15;
                int row = m0 + wm * 64 + mt * 16 + quad * 4;
                int bb = row >> 12, n = row & 4095;
                float bias = bhv[hch];
                bf16x4 pk = { f2bf(acc[mt][nt][0] + bias), f2bf(acc[mt][nt][1] + bias),
                              f2bf(acc[mt][nt][2] + bias), f2bf(acc[mt][nt][3] + bias) };
                *(bf16x4*)&hT[((size_t)(bb * 256 + hch)) * 4096 + n] = pk;
            }
        }
    }
}

// ---------------------------------------------------------------------------
// Kernel 2: attention v8.  Wave = 64 q x 128 vch, kv-split 2, grid 256,
// LB(256,1) (no spill; ~300 VGPR of 512). gl_lds staging + XOR swizzle.
// In-wave pipelining: S(A), S(B), softmax(A), PV(A), softmax(B), PV(B);
// half order staggered by wave parity to desync the shared CU matrix pipe.
// ---------------------------------------------------------------------------
__global__ __launch_bounds__(256, 1) void attn_v8(
    const short* __restrict__ fK,    // keys    [B*N,64]
    const short* __restrict__ gQ,    // queries [B*N,64] (pre-scaled by log2e)
    const short* __restrict__ hT,    // values  [B,256,4096]
    short* __restrict__ oPartB,      // [2][B*N,256] bf16
    float* __restrict__ lTot)        // [B*N] (pre-zeroed; atomic-accumulated)
{
    const int bx = blockIdx.x;
    const int s  = bx & 1;
    const int qt = (bx >> 1) & 31;
    const int b  = bx >> 6;
    const int kb = s * 2048;
    const int t  = threadIdx.x;
    const int w  = t >> 6, lane = t & 63;
    const int l31 = lane & 31, h = lane >> 5;
    const int wq = w & 1, wv = w >> 1;
    const int q_wave = qt * 128 + wq * 64;

    __shared__ short fs[2][64 * 64];     // keys  [key][d]  (swizzled chunks)
    __shared__ short hs[2][256 * 64];    // V^T   [vch][key] (swizzled chunks)

    const int wr = lane >> 3;                 // row within 8-row group
    const int kc = (lane & 7) ^ (wr & 7);     // logical key-chunk this lane fetches
    const int swz = l31 & 7;                  // read-side swizzle term

    // Q B-frags (B[k=d][n=q]: n=l31, k=16k+8h+j)
    bf16x8 qf[2][4];
    #pragma unroll
    for (int n2 = 0; n2 < 2; n2++)
        #pragma unroll
        for (int k = 0; k < 4; k++)
            qf[n2][k] = *(const bf16x8*)&gQ[(size_t)(b * N_ + q_wave + n2 * 32 + l31) * 64 + k * 16 + h * 8];

    floatx16 oacc[2][4];   // [n2][vt]: 64 q x 128 vch
    #pragma unroll
    for (int n2 = 0; n2 < 2; n2++)
        #pragma unroll
        for (int vt = 0; vt < 4; vt++)
            #pragma unroll
            for (int j = 0; j < 16; j++) oacc[n2][vt][j] = 0.f;
    float lsum[2] = {0.f, 0.f};

    // prologue: stage tile 0 (async) then barrier
    {
        #pragma unroll
        for (int j = 0; j < 2; j++) {
            int cc = w * 2 + j;
            int r = cc * 8 + wr;
            gl_lds16(&fK[(size_t)(b * N_ + kb + r) * 64 + kc * 8], &fs[0][cc * 512]);
        }
        #pragma unroll
        for (int j = 0; j < 8; j++) {
            int cc = w * 8 + j;
            int r = cc * 8 + wr;
            gl_lds16(&hT[((size_t)(b * 256 + r)) * 4096 + kb + kc * 8], &hs[0][cc * 512]);
        }
    }
    __syncthreads();

    const int mA = w & 1, mB = mA ^ 1;   // wave-staggered half order

    for (int it = 0; it < 32; ++it) {
        const int cur = it & 1;
        const int nxt = cur ^ 1;
        const bool more = (it < 31);
        const int kn = kb + (it + 1) * 64;

        // issue async staging for next tile (drained by end-of-iter barrier)
        if (more) {
            #pragma unroll
            for (int j = 0; j < 2; j++) {
                int cc = w * 2 + j;
                int r = cc * 8 + wr;
                gl_lds16(&fK[(size_t)(b * N_ + kn + r) * 64 + kc * 8], &fs[nxt][cc * 512]);
            }
            #pragma unroll
            for (int j = 0; j < 8; j++) {
                int cc = w * 8 + j;
                int r = cc * 8 + wr;
                gl_lds16(&hT[((size_t)(b * 256 + r)) * 4096 + kn + kc * 8], &hs[nxt][cc * 512]);
            }
        }

        // ---- S for half A (8 MFMAs) ----
        floatx16 sA[2];
        {
            bf16x8 ffr[4];
            #pragma unroll
            for (int k = 0; k < 4; k++)
                ffr[k] = *(const bf16x8*)&fs[cur][(mA * 32 + l31) * 64 + (((2 * k + h) ^ swz) * 8)];
            #pragma unroll
            for (int n2 = 0; n2 < 2; n2++)
                #pragma unroll
                for (int j = 0; j < 16; j++) sA[n2][j] = 0.f;
            #pragma unroll
            for (int k = 0; k < 4; k++)
                #pragma unroll
                for (int n2 = 0; n2 < 2; n2++)
                    sA[n2] = __builtin_amdgcn_mfma_f32_32x32x16_bf16(ffr[k], qf[n2][k], sA[n2], 0, 0, 0);
        }
        // ---- S for half B (8 MFMAs, independent of softmax(A)) ----
        floatx16 sB[2];
        {
            bf16x8 ffr[4];
            #pragma unroll
            for (int k = 0; k < 4; k++)
                ffr[k] = *(const bf16x8*)&fs[cur][(mB * 32 + l31) * 64 + (((2 * k + h) ^ swz) * 8)];
            #pragma unroll
            for (int n2 = 0; n2 < 2; n2++)
                #pragma unroll
                for (int j = 0; j < 16; j++) sB[n2][j] = 0.f;
            #pragma unroll
            for (int k = 0; k < 4; k++)
                #pragma unroll
                for (int n2 = 0; n2 < 2; n2++)
                    sB[n2] = __builtin_amdgcn_mfma_f32_32x32x16_bf16(ffr[k], qf[n2][k], sB[n2], 0, 0, 0);
        }

        // ---- softmax(A) (VALU; overlaps S(B) MFMAs) ----
        bf16x8 pfA[2][2];
        #pragma unroll
        for (int n2 = 0; n2 < 2; n2++) {
            float p[16]; float ps_ = 0.f;
            #pragma unroll
            for (int j = 0; j < 16; j++) { p[j] = exp2f(sA[n2][j]); ps_ += p[j]; }
            ps_ += __shfl_xor(ps_, 32);
            lsum[n2] += ps_;
            unsigned pk[8], xk[8];
            #pragma unroll
            for (int i = 0; i < 8; i++) pk[i] = pack2bf_fast(p[2 * i], p[2 * i + 1]);
            #pragma unroll
            for (int i = 0; i < 8; i++) xk[i] = __shfl_xor(pk[i], 32);
            #pragma unroll
            for (int kp = 0; kp < 2; kp++) {
                U8 u;
                u.u[0] = h ? xk[4 * kp + 2] : pk[4 * kp];
                u.u[1] = h ? xk[4 * kp + 3] : pk[4 * kp + 1];
                u.u[2] = h ? pk[4 * kp + 2] : xk[4 * kp];
                u.u[3] = h ? pk[4 * kp + 3] : xk[4 * kp + 1];
                pfA[n2][kp] = u.v;
            }
        }

        // ---- PV(A) (16 MFMAs) ----
        #pragma unroll
        for (int kp = 0; kp < 2; kp++) {
            const int kk = mA * 2 + kp;
            #pragma unroll
            for (int vt = 0; vt < 4; vt++) {
                bf16x8 vfr = *(const bf16x8*)&hs[cur][(wv * 128 + vt * 32 + l31) * 64 + (((2 * kk + h) ^ swz) * 8)];
                #pragma unroll
                for (int n2 = 0; n2 < 2; n2++)
                    oacc[n2][vt] = __builtin_amdgcn_mfma_f32_32x32x16_bf16(pfA[n2][kp], vfr, oacc[n2][vt], 0, 0, 0);
            }
        }

        // ---- softmax(B) (VALU; overlaps PV(A) MFMAs) ----
        bf16x8 pfB[2][2];
        #pragma unroll
        for (int n2 = 0; n2 < 2; n2++) {
            float p[16]; float ps_ = 0.f;
            #pragma unroll
            for (int j = 0; j < 16; j++) { p[j] = exp2f(sB[n2][j]); ps_ += p[j]; }
            ps_ += __shfl_xor(ps_, 32);
            lsum[n2] += ps_;
            unsigned pk[8], xk[8];
            #pragma unroll
            for (int i = 0; i < 8; i++) pk[i] = pack2bf_fast(p[2 * i], p[2 * i + 1]);
            #pragma unroll
            for (int i = 0; i < 8; i++) xk[i] = __shfl_xor(pk[i], 32);
            #pragma unroll
            for (int kp = 0; kp < 2; kp++) {
                U8 u;
                u.u[0] = h ? xk[4 * kp + 2] : pk[4 * kp];
                u.u[1] = h ? xk[4 * kp + 3] : pk[4 * kp + 1];
                u.u[2] = h ? pk[4 * kp + 2] : xk[4 * kp];
                u.u[3] = h ? pk[4 * kp + 3] : xk[4 * kp + 1];
                pfB[n2][kp] = u.v;
            }
        }

        // ---- PV(B) (16 MFMAs) ----
        #pragma unroll
        for (int kp = 0; kp < 2; kp++) {
            const int kk = mB * 2 + kp;
            #pragma unroll
            for (int vt = 0; vt < 4; vt++) {
                bf16x8 vfr = *(const bf16x8*)&hs[cur][(wv * 128 + vt * 32 + l31) * 64 + (((2 * kk + h) ^ swz) * 8)];
                #pragma unroll
                for (int n2 = 0; n2 < 2; n2++)
                    oacc[n2][vt] = __builtin_amdgcn_mfma_f32_32x32x16_bf16(pfB[n2][kp], vfr, oacc[n2][vt], 0, 0, 0);
            }
        }

        __syncthreads();   // drains vmcnt -> nxt tile ready
    }

    // ---- epilogue: store partial O (bf16); accumulate l atomically ----
    #pragma unroll
    for (int n2 = 0; n2 < 2; n2++) {
        #pragma unroll
        for (int vt = 0; vt < 4; vt++) {
            int vch = wv * 128 + vt * 32 + l31;
            #pragma unroll
            for (int r = 0; r < 16; r++) {
                int q = q_wave + n2 * 32 + (r & 3) + 8 * (r >> 2) + 4 * h;
                oPartB[(size_t)s * 4194304 + (size_t)(b * N_ + q) * 256 + vch] = f2bf(oacc[n2][vt][r]);
            }
        }
    }
    if (wv == 0 && lane < 32) {
        #pragma unroll
        for (int n2 = 0; n2 < 2; n2++)
            atomicAdd(&lTot[b * N_ + q_wave + n2 * 32 + lane], lsum[n2]);
    }
}

// ---------------------------------------------------------------------------
// Kernel 3: out = gamma*((O0+O1)/l @ Wo + bo) + x.  Combine fused into
// A-staging (sum 2 bf16 partials); 1/l applied per output row in epilogue.
// ---------------------------------------------------------------------------
__global__ __launch_bounds__(256, 2) void out_mfma(
    const short* __restrict__ oPartB, const float* __restrict__ lTot,
    const short* __restrict__ WoT,
    const float* __restrict__ bo, const float* __restrict__ x,
    const float* __restrict__ gamma, float* __restrict__ out)
{
    const int n0 = blockIdx.x * 128;
    const int m0 = blockIdx.y * 128;
    const int t  = threadIdx.x;
    const int w  = t >> 6, lane = t & 63;
    const int l15 = lane & 15, quad = lane >> 4;
    const int wm = w & 1, wn = w >> 1;

    __shared__ short As[2][128 * 40];
    __shared__ short Bs[2][128 * 40];

    const int r_row = t >> 1, r_ko = (t & 1) * 16;

    floatx4 acc[4][4];
    #pragma unroll
    for (int i = 0; i < 4; i++)
        #pragma unroll
        for (int j = 0; j < 4; j++) acc[i][j] = (floatx4){0.f,0.f,0.f,0.f};

    bf16x8 pp[2][2];   // 2 chunks x 2 splits
    bf16x8 bvv[2];

    #pragma unroll
    for (int i = 0; i < 2; i++) {
        size_t base = (size_t)(m0 + r_row) * 256 + r_ko + i * 8;
        pp[i][0] = *(const bf16x8*)&oPartB[base];
        pp[i][1] = *(const bf16x8*)&oPartB[base + 4194304];
        bvv[i] = *(const bf16x8*)&WoT[(size_t)(n0 + r_row) * 256 + r_ko + i * 8];
    }
    #pragma unroll
    for (int i = 0; i < 2; i++) {
        U8 u;
        #pragma unroll
        for (int jj = 0; jj < 4; jj++) {
            float e0 = bf2f(pp[i][0][2*jj])   + bf2f(pp[i][1][2*jj]);
            float e1 = bf2f(pp[i][0][2*jj+1]) + bf2f(pp[i][1][2*jj+1]);
            u.u[jj] = pack2bf_fast(e0, e1);
        }
        *(bf16x8*)&As[0][r_row * 40 + r_ko + i * 8] = u.v;
        *(bf16x8*)&Bs[0][r_row * 40 + r_ko + i * 8] = bvv[i];
    }

    for (int it = 0; it < 8; ++it) {
        const int cur = it & 1;
        const bool more = (it < 7);
        const int kn = (it + 1) * 32;
        __syncthreads();

        if (more) {
            #pragma unroll
            for (int i = 0; i < 2; i++) {
                size_t base = (size_t)(m0 + r_row) * 256 + kn + r_ko + i * 8;
                pp[i][0] = *(const bf16x8*)&oPartB[base];
                pp[i][1] = *(const bf16x8*)&oPartB[base + 4194304];
                bvv[i] = *(const bf16x8*)&WoT[(size_t)(n0 + r_row) * 256 + kn + r_ko + i * 8];
            }
        }

        bf16x8 af[4], bfr[4];
        #pragma unroll
        for (int mt = 0; mt < 4; mt++)
            af[mt] = *(const bf16x8*)&As[cur][(wm * 64 + mt * 16 + l15) * 40 + quad * 8];
        #pragma unroll
        for (int nt = 0; nt < 4; nt++)
            bfr[nt] = *(const bf16x8*)&Bs[cur][(wn * 64 + nt * 16 + l15) * 40 + quad * 8];
        #pragma unroll
        for (int mt = 0; mt < 4; mt++)
            #pragma unroll
            for (int nt = 0; nt < 4; nt++)
                acc[mt][nt] = __builtin_amdgcn_mfma_f32_16x16x32_bf16(af[mt], bfr[nt], acc[mt][nt], 0, 0, 0);

        if (more) {
            const int nxt = cur ^ 1;
            #pragma unroll
            for (int i = 0; i < 2; i++) {
                U8 u;
                #pragma unroll
                for (int jj = 0; jj < 4; jj++) {
                    float e0 = bf2f(pp[i][0][2*jj])   + bf2f(pp[i][1][2*jj]);
                    float e1 = bf2f(pp[i][0][2*jj+1]) + bf2f(pp[i][1][2*jj+1]);
                    u.u[jj] = pack2bf_fast(e0, e1);
                }
                *(bf16x8*)&As[nxt][r_row * 40 + r_ko + i * 8] = u.v;
                *(bf16x8*)&Bs[nxt][r_row * 40 + r_ko + i * 8] = bvv[i];
            }
        }
    }

    const float gm = gamma[0];
    #pragma unroll
    for (int mt = 0; mt < 4; mt++) {
        float inv[4];
        #pragma unroll
        for (int rg = 0; rg < 4; rg++)
            inv[rg] = 1.0f / lTot[m0 + wm * 64 + mt * 16 + quad * 4 + rg];
        #pragma unroll
        for (int nt = 0; nt < 4; nt++) {
            int col = n0 + wn * 64 + nt * 16 + l15;
            float bias = bo[col];
            #pragma unroll
            for (int rg = 0; rg < 4; rg++) {
                int row = m0 + wm * 64 + mt * 16 + quad * 4 + rg;
                out[(size_t)row * C_ + col] =
                    gm * (acc[mt][nt][rg] * inv[rg] + bias) + x[(size_t)row * C_ + col];
            }
        }
    }
}

// ---------------------------------------------------------------------------
extern "C" void kernel_launch(void* const* d_in, const int* in_sizes, int n_in,
                              void* d_out, int out_size, void* d_ws, size_t ws_size,
                              hipStream_t stream) {
    (void)in_sizes; (void)n_in; (void)out_size; (void)ws_size;

    const float* x     = (const float*)d_in[0];
    const float* Wf    = (const float*)d_in[1];
    const float* bfv   = (const float*)d_in[2];
    const float* Wg    = (const float*)d_in[3];
    const float* bgv   = (const float*)d_in[4];
    const float* Wh    = (const float*)d_in[5];
    const float* bhv   = (const float*)d_in[6];
    const float* Wo    = (const float*)d_in[7];
    const float* bo    = (const float*)d_in[8];
    const float* gamma = (const float*)d_in[9];
    float* out = (float*)d_out;

    // ws (shorts): fbf 1M | gbf 1M | hT 4M | WcatT 192K | WoT 128K |
    // oPartB 8.39M shorts | lTot 16K floats
    short* fbf    = (short*)d_ws;
    short* gbf    = fbf    + (size_t)B_ * N_ * C8_;
    short* hT     = gbf    + (size_t)B_ * N_ * C8_;
    short* WcatT  = hT     + (size_t)B_ * C2_ * N_;
    short* WoT    = WcatT  + (size_t)384 * 512;
    short* oPartB = WoT    + (size_t)512 * 256;
    float* lTot   = (float*)(oPartB + (size_t)2 * 16384 * 256);

    convert_w<<<1280, 256, 0, stream>>>(Wf, Wg, Wh, Wo, WcatT, WoT, lTot);
    qkv_mfma<<<dim3(3, 128), 256, 0, stream>>>(x, WcatT, bfv, bgv, bhv, fbf, gbf, hT);
    attn_v8<<<256, 256, 0, stream>>>(fbf, gbf, hT, oPartB, lTot);
    out_mfma<<<dim3(4, 128), 256, 0, stream>>>(oPartB, lTot, WoT, bo, x, gamma, out);
}